// Round 8
// baseline (443.599 us; speedup 1.0000x reference)
//
#include <hip/hip_runtime.h>

#define N_NODES 100000
#define N_EDGES 600000
#define N_GRAPHS 64
#define EPS 1e-5f
#define SCAN_BLOCKS 391  // ceil(N_NODES/256)

typedef unsigned short u16;
typedef unsigned int u32;
typedef __attribute__((ext_vector_type(8))) short bf16x8;
typedef __attribute__((ext_vector_type(4))) float f32x4;

// ---------- bf16 helpers ----------
__device__ __forceinline__ float bf2f(u16 u) { return __uint_as_float(((u32)u) << 16); }
__device__ __forceinline__ u16 f2bf(float f) {
    u32 u = __float_as_uint(f);
    u += 0x7FFFu + ((u >> 16) & 1u);
    return (u16)(u >> 16);
}
__device__ __forceinline__ float2 bfx2(u32 v) {
    float2 r;
    r.x = __uint_as_float(v << 16);
    r.y = __uint_as_float(v & 0xFFFF0000u);
    return r;
}
__device__ __forceinline__ void load_lds16(const void* g, void* l) {
    __builtin_amdgcn_global_load_lds((const __attribute__((address_space(1))) void*)g,
                                     (__attribute__((address_space(3))) void*)l, 16, 0, 0);
}

// ---------- workspace layout (bytes, 512-aligned) ----------
// zeroed region first
#define WS_COUNTS   ((size_t)0)          // int[N]
#define WS_CURSOR   ((size_t)400384)     // int[N]
#define WS_POOLED   ((size_t)800768)     // u32[64*128] (float bits, >=0)
#define WS_BNSUM    ((size_t)833536)     // float[128]
#define WS_BNSUMSQ  ((size_t)834048)     // float[128]
#define WS_FLAG     ((size_t)834560)     // int (1 = inputs are bf16, 0 = f32)
#define ZERO_BYTES  ((size_t)835072)
// non-zeroed
#define WS_OFFSETS  ((size_t)835072)     // int[N+1]
#define WS_DINV     ((size_t)1235456)    // float[N]
#define WS_DINV2    ((size_t)1635840)    // float[N]; start doubles as scan partials (dead by then)
#define WS_SRCS     ((size_t)2036224)    // int[E]
#define WS_ZF       ((size_t)4436736)    // float[64*64]
#define WS_CANONW   ((size_t)4453120)    // u16[62465] canonical weights (W1-W4 TRANSPOSED)
#define WS_BUFA     ((size_t)4578560)    // bf16[N*128]
#define WS_BUFB     ((size_t)30178560)   // bf16[N*128]; canon-x aliases its start
// total ~53.2 MB

// canonical weight offsets (u16 units); W1..W4 stored transposed [n][k]
#define CW_W1 0
#define CW_B1 4096
#define CW_W2 4224
#define CW_B2 20608
#define CW_W3 20736
#define CW_B3 37120
#define CW_G1 37248
#define CW_BE1 37376
#define CW_W4 37504
#define CW_B4 53888
#define CW_W5 54016
#define CW_B5 62208
#define CW_G2 62272
#define CW_BE2 62336
#define CW_W6 62400
#define CW_B6 62464

// ---------- dtype detector: low u16 of each word plausible as bf16? ----------
__global__ void detect_kernel(const u32* __restrict__ xraw, int* __restrict__ flag) {
    __shared__ int cnt;
    if (threadIdx.x == 0) cnt = 0;
    __syncthreads();
    int c = 0;
    for (int i = threadIdx.x; i < 2048; i += 256) {
        u32 w = xraw[i];
        float a = fabsf(__uint_as_float((w & 0xFFFFu) << 16));
        if (a == 0.f || (a > 1e-8f && a < 1e4f)) c++;
    }
    atomicAdd(&cnt, c);
    __syncthreads();
    if (threadIdx.x == 0) *flag = (cnt > 1024) ? 1 : 0;
}

// ---------- canonicalize x to bf16 ----------
__global__ void convx_kernel(const void* __restrict__ xsrc, u16* __restrict__ dst,
                             const int* __restrict__ flag) {
    int i = blockIdx.x * 256 + threadIdx.x;
    if (i < N_NODES * 32)
        dst[i] = (*flag) ? ((const u16*)xsrc)[i] : f2bf(((const float*)xsrc)[i]);
}

// ---------- canonicalize 16 weight arrays to bf16 (optionally transposed) ----------
struct SmallArgs {
    const void* src[16];
    int n[16];
    int off[16];
    int cols[16];  // >0: source is [K][cols] row-major; store transposed [cols][K]
};
__global__ void convs_kernel(SmallArgs a, u16* __restrict__ dst, const int* __restrict__ flag) {
    int i = blockIdx.x * 256 + threadIdx.x;
    int isbf = *flag;
#pragma unroll
    for (int j = 0; j < 16; j++)
        if (i < a.n[j]) {
            u16 v = isbf ? ((const u16*)a.src[j])[i] : f2bf(((const float*)a.src[j])[i]);
            if (a.cols[j] > 0) {
                int k = i / a.cols[j];
                int n = i - k * a.cols[j];
                int Kd = a.n[j] / a.cols[j];
                dst[a.off[j] + n * Kd + k] = v;
            } else {
                dst[a.off[j] + i] = v;
            }
        }
}

// ---------- degree histogram ----------
__global__ void deg_kernel(const int* __restrict__ dst, int* __restrict__ counts) {
    int e = blockIdx.x * 256 + threadIdx.x;
    if (e < N_EDGES) atomicAdd(&counts[dst[e]], 1);
}

// ---------- hierarchical scan: phase 1, per-block sums ----------
__global__ __launch_bounds__(256) void reduce_kernel(const int* __restrict__ counts,
                                                     int* __restrict__ partials) {
    int i = blockIdx.x * 256 + threadIdx.x;
    int v = (i < N_NODES) ? counts[i] : 0;
    for (int off = 32; off > 0; off >>= 1) v += __shfl_down(v, off, 64);
    __shared__ int wsum[4];
    if ((threadIdx.x & 63) == 0) wsum[threadIdx.x >> 6] = v;
    __syncthreads();
    if (threadIdx.x == 0) partials[blockIdx.x] = wsum[0] + wsum[1] + wsum[2] + wsum[3];
}

// ---------- phase 2: exclusive scan of 391 partials, one block ----------
__global__ __launch_bounds__(512) void scanpart_kernel(int* __restrict__ partials) {
    __shared__ int sc[512];
    int t = threadIdx.x;
    int v = (t < SCAN_BLOCKS) ? partials[t] : 0;
    sc[t] = v;
    __syncthreads();
    for (int off = 1; off < 512; off <<= 1) {
        int u = (t >= off) ? sc[t - off] : 0;
        __syncthreads();
        sc[t] += u;
        __syncthreads();
    }
    if (t < SCAN_BLOCKS) partials[t] = sc[t] - v;  // exclusive
}

// ---------- phase 3: block scan + partial prefix -> offsets; also dinv ----------
__global__ __launch_bounds__(256) void offsets_kernel(const int* __restrict__ counts,
                                                      const int* __restrict__ partials,
                                                      int* __restrict__ offs,
                                                      float* __restrict__ dinv) {
    int i = blockIdx.x * 256 + threadIdx.x;
    int lane = threadIdx.x & 63, wv = threadIdx.x >> 6;
    int v = (i < N_NODES) ? counts[i] : 0;
    int sv = v;
    for (int off = 1; off < 64; off <<= 1) {
        int u = __shfl_up(sv, off, 64);
        if (lane >= off) sv += u;
    }
    __shared__ int wsum[4];
    if (lane == 63) wsum[wv] = sv;
    __syncthreads();
    int wpre = 0;
    for (int w = 0; w < wv; w++) wpre += wsum[w];
    int excl = sv - v + wpre + partials[blockIdx.x];
    if (i < N_NODES) {
        offs[i] = excl;
        dinv[i] = rsqrtf((float)(v + 1));
    }
    if (i == N_NODES - 1) offs[N_NODES] = excl + v;
}

// ---------- scatter edges into CSR by dst ----------
__global__ void scatter_kernel(const int* __restrict__ src, const int* __restrict__ dst,
                               const int* __restrict__ offs, int* __restrict__ cursor,
                               int* __restrict__ srcs) {
    int e = blockIdx.x * 256 + threadIdx.x;
    if (e < N_EDGES) {
        int d = dst[e];
        int p = offs[d] + atomicAdd(&cursor[d], 1);
        srcs[p] = src[e];
    }
}

// ---------- MFMA GEMM: C[M,128] = epilogue(A[M,K] @ W[K,128]), W given transposed ----------
// 512 threads = 8 waves; block covers 128 rows; each wave owns ONE 16-row x 128-col tile
// (8 MFMA col-tiles, acc = 32 VGPRs). 8 waves/block -> up to 24-32 waves/CU resident for
// latency hiding (the 4-wave variants were stuck at ~6 waves/CU, everything idle).
// LDS W in fragment-major order, async-staged (global_load_lds, lane-ordered dst).
// SWAP=1: mfma(W,A) -> D node=lane&15, col=quad*4+reg => 8B uint2 C-stores.
// SWAP=0: mfma(A,W) -> D col=lane&15, node=quad*4+reg (OUT_MODE 2, no C store).
// IN_MODE 1: a = bf16(relu(A*scl[k]+shf[k]))
// OUT_MODE 0: C=acc*dscale[r]; 1: C=acc+bias + BN stats; 2: relu(acc+bias)->atomicMax pooled
template <int K, int IN_MODE, int OUT_MODE, int SWAP>
__global__ __launch_bounds__(512, 4) void mgemm_kernel(
    const u16* __restrict__ A, const u16* __restrict__ Wt, const u16* __restrict__ bias,
    u16* __restrict__ C, const float* __restrict__ scl, const float* __restrict__ shf,
    const float* __restrict__ dscale, float* __restrict__ bn_sum,
    float* __restrict__ bn_sumsq, const int* __restrict__ batch, u32* __restrict__ pooled,
    int M) {
    constexpr int NKT = K / 32;
    __shared__ __align__(16) u16 Wf[NKT * 8 * 512];
    __shared__ float csum[128], csumsq[128];

    const int tid = threadIdx.x;
    const int wave = __builtin_amdgcn_readfirstlane(tid >> 6);
    const int lane = tid & 63;
    const int l15 = lane & 15;
    const int quad = lane >> 4;
    const int row0 = blockIdx.x * 128 + wave * 16;

    // async stage W fragments into LDS (each instr: 64 lanes x 16B = 1KB)
    for (int f = wave; f < NKT * 8; f += 8) {
        int kt = f >> 3, nt = f & 7;
        const u16* g = Wt + (nt * 16 + l15) * K + kt * 32 + quad * 8;
        load_lds16(g, (void*)(Wf + f * 512));
    }
    if (OUT_MODE == 1 && tid < 128) { csum[tid] = 0.f; csumsq[tid] = 0.f; }
    __syncthreads();  // drains staging

    // A fragment loads (pipelined against kt loop by compiler vmcnt)
    const int rr = min(row0 + l15, M - 1);
    const u16* ap = A + (size_t)rr * K + quad * 8;
    uint4 araw[NKT];
#pragma unroll
    for (int kt = 0; kt < NKT; kt++) araw[kt] = *(const uint4*)(ap + kt * 32);

    f32x4 acc[8];
#pragma unroll
    for (int nt = 0; nt < 8; nt++) acc[nt] = {0.f, 0.f, 0.f, 0.f};

#pragma unroll
    for (int kt = 0; kt < NKT; kt++) {
        bf16x8 af;
        if (IN_MODE == 0) {
            af = __builtin_bit_cast(bf16x8, araw[kt]);
        } else {
            float4 sa = *(const float4*)(scl + kt * 32 + quad * 8);
            float4 sb = *(const float4*)(scl + kt * 32 + quad * 8 + 4);
            float4 ha = *(const float4*)(shf + kt * 32 + quad * 8);
            float4 hb = *(const float4*)(shf + kt * 32 + quad * 8 + 4);
            float se[8] = {sa.x, sa.y, sa.z, sa.w, sb.x, sb.y, sb.z, sb.w};
            float he[8] = {ha.x, ha.y, ha.z, ha.w, hb.x, hb.y, hb.z, hb.w};
            u32 w4[4] = {araw[kt].x, araw[kt].y, araw[kt].z, araw[kt].w};
            bf16x8 tmp;
#pragma unroll
            for (int t = 0; t < 4; t++) {
                float2 f = bfx2(w4[t]);
                f.x = fmaxf(fmaf(f.x, se[2 * t], he[2 * t]), 0.f);
                f.y = fmaxf(fmaf(f.y, se[2 * t + 1], he[2 * t + 1]), 0.f);
                tmp[2 * t] = (short)f2bf(f.x);
                tmp[2 * t + 1] = (short)f2bf(f.y);
            }
            af = tmp;
        }
#pragma unroll
        for (int nt = 0; nt < 8; nt++) {
            bf16x8 wf = *(const bf16x8*)&Wf[(kt * 8 + nt) * 512 + lane * 8];
            if (SWAP)
                acc[nt] = __builtin_amdgcn_mfma_f32_16x16x32_bf16(wf, af, acc[nt], 0, 0, 0);
            else
                acc[nt] = __builtin_amdgcn_mfma_f32_16x16x32_bf16(af, wf, acc[nt], 0, 0, 0);
        }
    }

    if (OUT_MODE == 0) {  // SWAP=1 layout: node=l15, col=quad*4+i
        int r = row0 + l15;
        if (r < M) {
            float ds = dscale[r];
            u16* cp = C + (size_t)r * 128 + quad * 4;
#pragma unroll
            for (int nt = 0; nt < 8; nt++) {
                uint2 pk;
                pk.x = (u32)f2bf(acc[nt][0] * ds) | ((u32)f2bf(acc[nt][1] * ds) << 16);
                pk.y = (u32)f2bf(acc[nt][2] * ds) | ((u32)f2bf(acc[nt][3] * ds) << 16);
                *(uint2*)(cp + nt * 16) = pk;
            }
        }
    } else if (OUT_MODE == 1) {  // SWAP=1 layout
        float s[8][4], sq[8][4];
        int r = row0 + l15;
        bool valid = r < M;
        u16* cp = C + (size_t)min(r, M - 1) * 128 + quad * 4;
#pragma unroll
        for (int nt = 0; nt < 8; nt++) {
            uint2 br = *(const uint2*)(bias + nt * 16 + quad * 4);
            float2 b01 = bfx2(br.x), b23 = bfx2(br.y);
            float b[4] = {b01.x, b01.y, b23.x, b23.y};
            float v[4];
#pragma unroll
            for (int i = 0; i < 4; i++) {
                v[i] = acc[nt][i] + b[i];
                s[nt][i] = valid ? v[i] : 0.f;
                sq[nt][i] = valid ? v[i] * v[i] : 0.f;
            }
            if (valid) {
                uint2 pk;
                pk.x = (u32)f2bf(v[0]) | ((u32)f2bf(v[1]) << 16);
                pk.y = (u32)f2bf(v[2]) | ((u32)f2bf(v[3]) << 16);
                *(uint2*)(cp + nt * 16) = pk;
            }
        }
#pragma unroll
        for (int m = 1; m < 16; m <<= 1)
#pragma unroll
            for (int nt = 0; nt < 8; nt++)
#pragma unroll
                for (int i = 0; i < 4; i++) {
                    s[nt][i] += __shfl_xor(s[nt][i], m, 64);
                    sq[nt][i] += __shfl_xor(sq[nt][i], m, 64);
                }
        if (l15 == 0)
#pragma unroll
            for (int nt = 0; nt < 8; nt++)
#pragma unroll
                for (int i = 0; i < 4; i++) {
                    atomicAdd(&csum[nt * 16 + quad * 4 + i], s[nt][i]);
                    atomicAdd(&csumsq[nt * 16 + quad * 4 + i], sq[nt][i]);
                }
        __syncthreads();
        if (tid < 128) {
            atomicAdd(&bn_sum[tid], csum[tid]);
            atomicAdd(&bn_sumsq[tid], csumsq[tid]);
        }
    } else {  // OUT_MODE 2, SWAP=0 layout: col=nt*16+l15, node=quad*4+i
        float b[8];
#pragma unroll
        for (int nt = 0; nt < 8; nt++) b[nt] = bf2f(bias[nt * 16 + l15]);
        float cur[8];
#pragma unroll
        for (int nt = 0; nt < 8; nt++) cur[nt] = 0.f;
        int curg = -1;
#pragma unroll
        for (int i = 0; i < 4; i++) {
            int r = row0 + quad * 4 + i;
            if (r < M) {
                int g = batch[r];
                if (g != curg) {
                    if (curg >= 0) {
                        u32* bp = pooled + curg * 128 + l15;
#pragma unroll
                        for (int nt = 0; nt < 8; nt++)
                            if (cur[nt] > 0.f) atomicMax(&bp[nt * 16], __float_as_uint(cur[nt]));
                    }
                    curg = g;
#pragma unroll
                    for (int nt = 0; nt < 8; nt++) cur[nt] = 0.f;
                }
#pragma unroll
                for (int nt = 0; nt < 8; nt++)
                    cur[nt] = fmaxf(cur[nt], fmaxf(acc[nt][i] + b[nt], 0.f));
            }
        }
        if (curg >= 0) {
            u32* bp = pooled + curg * 128 + l15;
#pragma unroll
            for (int nt = 0; nt < 8; nt++)
                if (cur[nt] > 0.f) atomicMax(&bp[nt * 16], __float_as_uint(cur[nt]));
        }
    }
}

// ---------- conv aggregation over pre-scaled rows hs = h*dinv ----------
// xout = relu((Σ_src hs[src] + hs[own]) * dinv[own] + b)
__global__ __launch_bounds__(256) void conv_kernel(const u16* __restrict__ hs,
                                                   const int* __restrict__ srcs,
                                                   const int* __restrict__ offs,
                                                   const float* __restrict__ dinv,
                                                   const u16* __restrict__ bias,
                                                   u16* __restrict__ xout) {
    int wid = (blockIdx.x * 256 + threadIdx.x) >> 6;
    int lane = threadIdx.x & 63;
    if (wid >= N_NODES) return;
    int l = lane & 15, g = lane >> 4;
    int e0 = offs[wid], e1 = offs[wid + 1];
    float acc[8] = {0.f, 0.f, 0.f, 0.f, 0.f, 0.f, 0.f, 0.f};
    for (int e = e0 + g; e < e1; e += 4) {
        int s = srcs[e];
        uint4 raw = *(const uint4*)(hs + (size_t)s * 128 + l * 8);
        u32 w[4] = {raw.x, raw.y, raw.z, raw.w};
#pragma unroll
        for (int t = 0; t < 4; t++) {
            float2 f = bfx2(w[t]);
            acc[2 * t] += f.x;
            acc[2 * t + 1] += f.y;
        }
    }
#pragma unroll
    for (int j = 0; j < 8; j++) {
        acc[j] += __shfl_xor(acc[j], 16, 64);
        acc[j] += __shfl_xor(acc[j], 32, 64);
    }
    if (g == 0) {
        float di = dinv[wid];
        uint4 own = *(const uint4*)(hs + (size_t)wid * 128 + l * 8);
        uint4 bb = *(const uint4*)(bias + l * 8);
        u32 ow[4] = {own.x, own.y, own.z, own.w};
        u32 bw[4] = {bb.x, bb.y, bb.z, bb.w};
        u32 res[4];
#pragma unroll
        for (int t = 0; t < 4; t++) {
            float2 fo = bfx2(ow[t]);
            float2 fb = bfx2(bw[t]);
            float rx = fmaxf(fmaf(acc[2 * t] + fo.x, di, fb.x), 0.f);
            float ry = fmaxf(fmaf(acc[2 * t + 1] + fo.y, di, fb.y), 0.f);
            res[t] = (u32)f2bf(rx) | ((u32)f2bf(ry) << 16);
        }
        uint4 outp = {res[0], res[1], res[2], res[3]};
        *(uint4*)(xout + (size_t)wid * 128 + l * 8) = outp;
    }
}

// ---------- BN stats -> scale/shift (in place) ----------
__global__ void bnstats_kernel(float* __restrict__ bn_sum, float* __restrict__ bn_sumsq,
                               const u16* __restrict__ g1, const u16* __restrict__ be1) {
    int c = threadIdx.x;
    if (c < 128) {
        float mu = bn_sum[c] / (float)N_NODES;
        float var = bn_sumsq[c] / (float)N_NODES - mu * mu;
        float rstd = rsqrtf(var + EPS);
        float sc = rstd * bf2f(g1[c]);
        bn_sum[c] = sc;
        bn_sumsq[c] = bf2f(be1[c]) - mu * sc;
    }
}

// ---------- head part 1: zf[64,64] = pooled[64,128] @ W5 + b5 ----------
__global__ __launch_bounds__(256) void head1_kernel(const u32* __restrict__ pooled,
                                                    const u16* __restrict__ W5,
                                                    const u16* __restrict__ b5,
                                                    float* __restrict__ zf) {
    __shared__ float red[4][64];
    int g = blockIdx.x;
    int c = threadIdx.x & 63;
    int kq = threadIdx.x >> 6;
    const u32* prow = pooled + g * 128;
    float p = 0.f;
    for (int k = kq * 32; k < kq * 32 + 32; k++)
        p = fmaf(__uint_as_float(prow[k]), bf2f(W5[k * 64 + c]), p);
    red[kq][c] = p;
    __syncthreads();
    if (kq == 0) zf[g * 64 + c] = red[0][c] + red[1][c] + red[2][c] + red[3][c] + bf2f(b5[c]);
}

// ---------- head part 2: BN over 64 graphs, relu, @W6 + b6; dtype-switched out ----------
__global__ __launch_bounds__(64) void head2_kernel(const float* __restrict__ zf,
                                                   const u16* __restrict__ g2,
                                                   const u16* __restrict__ be2,
                                                   const u16* __restrict__ W6,
                                                   const u16* __restrict__ b6,
                                                   void* __restrict__ outv,
                                                   const int* __restrict__ flag) {
    __shared__ float Z[64][65];
    __shared__ float sc[64], sh[64], w6[64];
    int t = threadIdx.x;
    for (int idx = t; idx < 4096; idx += 64) Z[idx >> 6][idx & 63] = zf[idx];
    w6[t] = bf2f(W6[t]);
    __syncthreads();
    {
        float s = 0.f, sq = 0.f;
        for (int g = 0; g < 64; g++) {
            float v = Z[g][t];
            s += v;
            sq += v * v;
        }
        float mu = s * (1.f / 64.f);
        float var = sq * (1.f / 64.f) - mu * mu;
        float rstd = rsqrtf(var + EPS);
        float scale = rstd * bf2f(g2[t]);
        sc[t] = scale;
        sh[t] = bf2f(be2[t]) - mu * scale;
    }
    __syncthreads();
    float o = 0.f;
    for (int c = 0; c < 64; c++)
        o = fmaf(fmaxf(fmaf(Z[t][c], sc[c], sh[c]), 0.f), w6[c], o);
    float res = o + bf2f(b6[0]);
    if (*flag)
        ((u16*)outv)[t] = f2bf(res);
    else
        ((float*)outv)[t] = res;
}

extern "C" void kernel_launch(void* const* d_in, const int* in_sizes, int n_in, void* d_out,
                              int out_size, void* d_ws, size_t ws_size, hipStream_t stream) {
    const void* x = d_in[0];
    const int* ei = (const int*)d_in[1];
    const int* bat = (const int*)d_in[2];

    char* ws = (char*)d_ws;
    int* counts = (int*)(ws + WS_COUNTS);
    int* cursor = (int*)(ws + WS_CURSOR);
    u32* pooled = (u32*)(ws + WS_POOLED);
    float* bnsum = (float*)(ws + WS_BNSUM);
    float* bnssq = (float*)(ws + WS_BNSUMSQ);
    int* flag = (int*)(ws + WS_FLAG);
    int* offs = (int*)(ws + WS_OFFSETS);
    float* dinv = (float*)(ws + WS_DINV);
    int* partials = (int*)(ws + WS_DINV2);  // dead region reuse
    int* srcs = (int*)(ws + WS_SRCS);
    float* zf = (float*)(ws + WS_ZF);
    u16* cw = (u16*)(ws + WS_CANONW);
    u16* bufA = (u16*)(ws + WS_BUFA);
    u16* bufB = (u16*)(ws + WS_BUFB);
    u16* canonx = bufB;  // aliases bufB: dead after gemm1, bufB first written by conv1

    const int* esrc = ei;
    const int* edst = ei + N_EDGES;

    hipMemsetAsync(ws, 0, ZERO_BYTES, stream);
    detect_kernel<<<1, 256, 0, stream>>>((const u32*)x, flag);

    // canonicalize inputs to bf16 (W1..W4 transposed for MFMA frag reads)
    convx_kernel<<<(N_NODES * 32 + 255) / 256, 256, 0, stream>>>(x, canonx, flag);
    SmallArgs sa;
    const int cw_off[16] = {CW_W1, CW_B1, CW_W2, CW_B2, CW_W3, CW_B3, CW_G1, CW_BE1,
                            CW_W4, CW_B4, CW_W5, CW_B5, CW_G2, CW_BE2, CW_W6, CW_B6};
    const int cw_n[16] = {4096, 128, 16384, 128, 16384, 128, 128, 128,
                          16384, 128, 8192, 64, 64, 64, 64, 1};
    const int cw_c[16] = {128, 0, 128, 0, 128, 0, 0, 0, 128, 0, 0, 0, 0, 0, 0, 0};
    for (int j = 0; j < 16; j++) {
        sa.src[j] = d_in[3 + j];
        sa.n[j] = cw_n[j];
        sa.off[j] = cw_off[j];
        sa.cols[j] = cw_c[j];
    }
    convs_kernel<<<64, 256, 0, stream>>>(sa, cw, flag);

    deg_kernel<<<(N_EDGES + 255) / 256, 256, 0, stream>>>(edst, counts);
    reduce_kernel<<<SCAN_BLOCKS, 256, 0, stream>>>(counts, partials);
    scanpart_kernel<<<1, 512, 0, stream>>>(partials);
    offsets_kernel<<<SCAN_BLOCKS, 256, 0, stream>>>(counts, partials, offs, dinv);
    scatter_kernel<<<(N_EDGES + 255) / 256, 256, 0, stream>>>(esrc, edst, offs, cursor, srcs);

    const int gb = (N_NODES + 127) / 128;
    const int cb = (N_NODES + 3) / 4;
    // conv1: hs1 = (x @ W1)*dinv ; x1 = relu((agg(hs1)+hs1)*dinv + b1)
    mgemm_kernel<32, 0, 0, 1><<<gb, 512, 0, stream>>>(canonx, cw + CW_W1, nullptr, bufA, nullptr,
                                                      nullptr, dinv, nullptr, nullptr, nullptr,
                                                      nullptr, N_NODES);
    conv_kernel<<<cb, 256, 0, stream>>>(bufA, srcs, offs, dinv, cw + CW_B1, bufB);
    // conv2
    mgemm_kernel<128, 0, 0, 1><<<gb, 512, 0, stream>>>(bufB, cw + CW_W2, nullptr, bufA, nullptr,
                                                       nullptr, dinv, nullptr, nullptr, nullptr,
                                                       nullptr, N_NODES);
    conv_kernel<<<cb, 256, 0, stream>>>(bufA, srcs, offs, dinv, cw + CW_B2, bufB);
    // y3 = x2 @ W3 + b3 (+ BN stats)
    mgemm_kernel<128, 0, 1, 1><<<gb, 512, 0, stream>>>(bufB, cw + CW_W3, cw + CW_B3, bufA,
                                                       nullptr, nullptr, nullptr, bnsum, bnssq,
                                                       nullptr, nullptr, N_NODES);
    bnstats_kernel<<<1, 128, 0, stream>>>(bnsum, bnssq, cw + CW_G1, cw + CW_BE1);
    // out4 = relu(relu(BN(y3)) @ W4 + b4) -> segment max into pooled
    mgemm_kernel<128, 1, 2, 0><<<gb, 512, 0, stream>>>(bufA, cw + CW_W4, cw + CW_B4, nullptr,
                                                       bnsum, bnssq, nullptr, nullptr, nullptr,
                                                       bat, pooled, N_NODES);
    // head
    head1_kernel<<<N_GRAPHS, 256, 0, stream>>>(pooled, cw + CW_W5, cw + CW_B5, zf);
    head2_kernel<<<1, 64, 0, stream>>>(zf, cw + CW_G2, cw + CW_BE2, cw + CW_W6, cw + CW_B6,
                                       d_out, flag);
}

// Round 9
// 366.051 us; speedup vs baseline: 1.2119x; 1.2119x over previous
//
#include <hip/hip_runtime.h>

#define N_NODES 100000
#define N_EDGES 600000
#define N_GRAPHS 64
#define EPS 1e-5f
#define SCAN_BLOCKS 391  // ceil(N_NODES/256)

typedef unsigned short u16;
typedef unsigned int u32;
typedef __attribute__((ext_vector_type(8))) short bf16x8;
typedef __attribute__((ext_vector_type(4))) float f32x4;

// ---------- bf16 helpers ----------
__device__ __forceinline__ float bf2f(u16 u) { return __uint_as_float(((u32)u) << 16); }
__device__ __forceinline__ u16 f2bf(float f) {
    u32 u = __float_as_uint(f);
    u += 0x7FFFu + ((u >> 16) & 1u);
    return (u16)(u >> 16);
}
__device__ __forceinline__ float2 bfx2(u32 v) {
    float2 r;
    r.x = __uint_as_float(v << 16);
    r.y = __uint_as_float(v & 0xFFFF0000u);
    return r;
}

// ---------- workspace layout (bytes, 512-aligned) ----------
// zeroed region first
#define WS_COUNTS   ((size_t)0)          // int[N]
#define WS_CURSOR   ((size_t)400384)     // int[N]
#define WS_POOLED   ((size_t)800768)     // u32[64*128] (float bits, >=0)
#define WS_BNSUM    ((size_t)833536)     // float[128]
#define WS_BNSUMSQ  ((size_t)834048)     // float[128]
#define WS_FLAG     ((size_t)834560)     // int (1 = inputs are bf16, 0 = f32)
#define ZERO_BYTES  ((size_t)835072)
// non-zeroed
#define WS_OFFSETS  ((size_t)835072)     // int[N+1]
#define WS_DINV     ((size_t)1235456)    // float[N]
#define WS_DINV2    ((size_t)1635840)    // float[N]; start doubles as scan partials (dead by then)
#define WS_SRCS     ((size_t)2036224)    // int[E]
#define WS_ZF       ((size_t)4436736)    // float[64*64]
#define WS_CANONW   ((size_t)4453120)    // u16[62465] canonical weights (W1-W4 TRANSPOSED)
#define WS_BUFA     ((size_t)4578560)    // bf16[N*128]
#define WS_BUFB     ((size_t)30178560)   // bf16[N*128]; canon-x aliases its start
// total ~53.2 MB

// canonical weight offsets (u16 units); W1..W4 stored transposed [n][k]
#define CW_W1 0
#define CW_B1 4096
#define CW_W2 4224
#define CW_B2 20608
#define CW_W3 20736
#define CW_B3 37120
#define CW_G1 37248
#define CW_BE1 37376
#define CW_W4 37504
#define CW_B4 53888
#define CW_W5 54016
#define CW_B5 62208
#define CW_G2 62272
#define CW_BE2 62336
#define CW_W6 62400
#define CW_B6 62464

// ---------- dtype detector ----------
__global__ void detect_kernel(const u32* __restrict__ xraw, int* __restrict__ flag) {
    __shared__ int cnt;
    if (threadIdx.x == 0) cnt = 0;
    __syncthreads();
    int c = 0;
    for (int i = threadIdx.x; i < 2048; i += 256) {
        u32 w = xraw[i];
        float a = fabsf(__uint_as_float((w & 0xFFFFu) << 16));
        if (a == 0.f || (a > 1e-8f && a < 1e4f)) c++;
    }
    atomicAdd(&cnt, c);
    __syncthreads();
    if (threadIdx.x == 0) *flag = (cnt > 1024) ? 1 : 0;
}

// ---------- canonicalize x to bf16 ----------
__global__ void convx_kernel(const void* __restrict__ xsrc, u16* __restrict__ dst,
                             const int* __restrict__ flag) {
    int i = blockIdx.x * 256 + threadIdx.x;
    if (i < N_NODES * 32)
        dst[i] = (*flag) ? ((const u16*)xsrc)[i] : f2bf(((const float*)xsrc)[i]);
}

// ---------- canonicalize 16 weight arrays to bf16 (optionally transposed) ----------
struct SmallArgs {
    const void* src[16];
    int n[16];
    int off[16];
    int cols[16];
};
__global__ void convs_kernel(SmallArgs a, u16* __restrict__ dst, const int* __restrict__ flag) {
    int i = blockIdx.x * 256 + threadIdx.x;
    int isbf = *flag;
#pragma unroll
    for (int j = 0; j < 16; j++)
        if (i < a.n[j]) {
            u16 v = isbf ? ((const u16*)a.src[j])[i] : f2bf(((const float*)a.src[j])[i]);
            if (a.cols[j] > 0) {
                int k = i / a.cols[j];
                int n = i - k * a.cols[j];
                int Kd = a.n[j] / a.cols[j];
                dst[a.off[j] + n * Kd + k] = v;
            } else {
                dst[a.off[j] + i] = v;
            }
        }
}

// ---------- degree histogram ----------
__global__ void deg_kernel(const int* __restrict__ dst, int* __restrict__ counts) {
    int e = blockIdx.x * 256 + threadIdx.x;
    if (e < N_EDGES) atomicAdd(&counts[dst[e]], 1);
}

// ---------- hierarchical scan: phase 1 ----------
__global__ __launch_bounds__(256) void reduce_kernel(const int* __restrict__ counts,
                                                     int* __restrict__ partials) {
    int i = blockIdx.x * 256 + threadIdx.x;
    int v = (i < N_NODES) ? counts[i] : 0;
    for (int off = 32; off > 0; off >>= 1) v += __shfl_down(v, off, 64);
    __shared__ int wsum[4];
    if ((threadIdx.x & 63) == 0) wsum[threadIdx.x >> 6] = v;
    __syncthreads();
    if (threadIdx.x == 0) partials[blockIdx.x] = wsum[0] + wsum[1] + wsum[2] + wsum[3];
}

// ---------- phase 2 ----------
__global__ __launch_bounds__(512) void scanpart_kernel(int* __restrict__ partials) {
    __shared__ int sc[512];
    int t = threadIdx.x;
    int v = (t < SCAN_BLOCKS) ? partials[t] : 0;
    sc[t] = v;
    __syncthreads();
    for (int off = 1; off < 512; off <<= 1) {
        int u = (t >= off) ? sc[t - off] : 0;
        __syncthreads();
        sc[t] += u;
        __syncthreads();
    }
    if (t < SCAN_BLOCKS) partials[t] = sc[t] - v;
}

// ---------- phase 3: offsets + dinv ----------
__global__ __launch_bounds__(256) void offsets_kernel(const int* __restrict__ counts,
                                                      const int* __restrict__ partials,
                                                      int* __restrict__ offs,
                                                      float* __restrict__ dinv) {
    int i = blockIdx.x * 256 + threadIdx.x;
    int lane = threadIdx.x & 63, wv = threadIdx.x >> 6;
    int v = (i < N_NODES) ? counts[i] : 0;
    int sv = v;
    for (int off = 1; off < 64; off <<= 1) {
        int u = __shfl_up(sv, off, 64);
        if (lane >= off) sv += u;
    }
    __shared__ int wsum[4];
    if (lane == 63) wsum[wv] = sv;
    __syncthreads();
    int wpre = 0;
    for (int w = 0; w < wv; w++) wpre += wsum[w];
    int excl = sv - v + wpre + partials[blockIdx.x];
    if (i < N_NODES) {
        offs[i] = excl;
        dinv[i] = rsqrtf((float)(v + 1));
    }
    if (i == N_NODES - 1) offs[N_NODES] = excl + v;
}

// ---------- scatter edges into CSR by dst ----------
__global__ void scatter_kernel(const int* __restrict__ src, const int* __restrict__ dst,
                               const int* __restrict__ offs, int* __restrict__ cursor,
                               int* __restrict__ srcs) {
    int e = blockIdx.x * 256 + threadIdx.x;
    if (e < N_EDGES) {
        int d = dst[e];
        int p = offs[d] + atomicAdd(&cursor[d], 1);
        srcs[p] = src[e];
    }
}

// ---------- MFMA GEMM (round-6 structure) + optional fused conv-gather A ----------
// 256 thr = 4 waves; block 128 rows x 128 cols; wave = 2 row-tiles x 8 col-tiles.
// W in LDS row-major padded (KP=K+8); staged with plain u32 loads (round-6 proven).
// C/D layout (mfma(A,W)): col=lane&15, row=quad*4+reg.
// IN_MODE 0: A read direct.  IN_MODE 1: a=bf16(relu(A*scl+shf)).
// IN_MODE 2 (FUSED CONV): a[r] = bf16(relu((Σ_src A[src] + A[r])*gdinv[r] + gbias)),
//   gathered per lane into f32 regs over the CSR edge list, then packed.
// OUT_MODE 0: C=acc*dscale[r]; 1: C=acc+bias + BN stats; 2: relu(acc+bias)->atomicMax pooled
template <int K, int IN_MODE, int OUT_MODE>
__global__ __launch_bounds__(256, 3) void mgemm_kernel(
    const u16* __restrict__ A, const u16* __restrict__ Wt, const u16* __restrict__ bias,
    u16* __restrict__ C, const float* __restrict__ scl, const float* __restrict__ shf,
    const float* __restrict__ dscale, float* __restrict__ bn_sum,
    float* __restrict__ bn_sumsq, const int* __restrict__ batch, u32* __restrict__ pooled,
    const int* __restrict__ goffs, const int* __restrict__ gsrcs,
    const float* __restrict__ gdinv, const u16* __restrict__ gbias, int M) {
    constexpr int KP = K + 8;
    constexpr int NKT = K / 32;
    __shared__ __align__(16) u16 Wl[128 * KP];
    __shared__ float csum[128], csumsq[128];

    const int tid = threadIdx.x;
    const int wave = tid >> 6;
    const int lane = tid & 63;
    const int l15 = lane & 15;
    const int quad = lane >> 4;
    const int row0 = blockIdx.x * 128 + wave * 32;

    {  // stage Wt -> LDS with padding, coalesced u32 (round-6 proven path)
        const u32* g = (const u32*)Wt;
        u32* l = (u32*)Wl;
        for (int i = tid; i < 128 * (K / 2); i += 256) {
            int n = i / (K / 2), j = i - n * (K / 2);
            l[n * (KP / 2) + j] = g[i];
        }
    }
    if (OUT_MODE == 1 && tid < 128) { csum[tid] = 0.f; csumsq[tid] = 0.f; }

    // fused conv gather: build packed A fragments in registers (no LDS involved)
    uint4 gr[2][NKT];
    if (IN_MODE == 2) {
#pragma unroll
        for (int rt = 0; rt < 2; rt++) {
            int r = min(row0 + rt * 16 + l15, M - 1);
            int e0 = goffs[r], e1 = goffs[r + 1];
            float ga[NKT][8];
#pragma unroll
            for (int kt = 0; kt < NKT; kt++)
#pragma unroll
                for (int j = 0; j < 8; j++) ga[kt][j] = 0.f;
            for (int e = e0; e < e1; e++) {
                int s = gsrcs[e];
                const u16* hp = A + (size_t)s * K + quad * 8;
#pragma unroll
                for (int kt = 0; kt < NKT; kt++) {
                    uint4 raw = *(const uint4*)(hp + kt * 32);
                    u32 w4[4] = {raw.x, raw.y, raw.z, raw.w};
#pragma unroll
                    for (int t = 0; t < 4; t++) {
                        float2 f = bfx2(w4[t]);
                        ga[kt][2 * t] += f.x;
                        ga[kt][2 * t + 1] += f.y;
                    }
                }
            }
            float di = gdinv[r];
            const u16* op = A + (size_t)r * K + quad * 8;
#pragma unroll
            for (int kt = 0; kt < NKT; kt++) {
                uint4 own = *(const uint4*)(op + kt * 32);
                uint4 bb = *(const uint4*)(gbias + kt * 32 + quad * 8);
                u32 ow[4] = {own.x, own.y, own.z, own.w};
                u32 bw[4] = {bb.x, bb.y, bb.z, bb.w};
                u32 pk[4];
#pragma unroll
                for (int t = 0; t < 4; t++) {
                    float2 fo = bfx2(ow[t]);
                    float2 fb = bfx2(bw[t]);
                    float vx = fmaxf(fmaf(ga[kt][2 * t] + fo.x, di, fb.x), 0.f);
                    float vy = fmaxf(fmaf(ga[kt][2 * t + 1] + fo.y, di, fb.y), 0.f);
                    pk[t] = (u32)f2bf(vx) | ((u32)f2bf(vy) << 16);
                }
                gr[rt][kt] = {pk[0], pk[1], pk[2], pk[3]};
            }
        }
    }
    __syncthreads();

    f32x4 acc[2][8];
#pragma unroll
    for (int rt = 0; rt < 2; rt++)
#pragma unroll
        for (int nt = 0; nt < 8; nt++) acc[rt][nt] = {0.f, 0.f, 0.f, 0.f};

#pragma unroll
    for (int k0 = 0; k0 < K; k0 += 32) {
        bf16x8 af[2];
        if (IN_MODE == 2) {
#pragma unroll
            for (int rt = 0; rt < 2; rt++) af[rt] = __builtin_bit_cast(bf16x8, gr[rt][k0 / 32]);
        } else if (IN_MODE == 0) {
#pragma unroll
            for (int rt = 0; rt < 2; rt++) {
                int r = min(row0 + rt * 16 + l15, M - 1);
                af[rt] = *(const bf16x8*)(A + (size_t)r * K + k0 + quad * 8);
            }
        } else {
            float s8[8], h8[8];
#pragma unroll
            for (int t = 0; t < 8; t++) {
                s8[t] = scl[k0 + quad * 8 + t];
                h8[t] = shf[k0 + quad * 8 + t];
            }
#pragma unroll
            for (int rt = 0; rt < 2; rt++) {
                int r = min(row0 + rt * 16 + l15, M - 1);
                uint4 raw = *(const uint4*)(A + (size_t)r * K + k0 + quad * 8);
                u32 w4[4] = {raw.x, raw.y, raw.z, raw.w};
                bf16x8 tmp;
#pragma unroll
                for (int t = 0; t < 4; t++) {
                    float2 f = bfx2(w4[t]);
                    f.x = fmaxf(fmaf(f.x, s8[2 * t], h8[2 * t]), 0.f);
                    f.y = fmaxf(fmaf(f.y, s8[2 * t + 1], h8[2 * t + 1]), 0.f);
                    tmp[2 * t] = (short)f2bf(f.x);
                    tmp[2 * t + 1] = (short)f2bf(f.y);
                }
                af[rt] = tmp;
            }
        }
#pragma unroll
        for (int nt = 0; nt < 8; nt++) {
            bf16x8 bf = *(const bf16x8*)&Wl[(nt * 16 + l15) * KP + k0 + quad * 8];
            acc[0][nt] = __builtin_amdgcn_mfma_f32_16x16x32_bf16(af[0], bf, acc[0][nt], 0, 0, 0);
            acc[1][nt] = __builtin_amdgcn_mfma_f32_16x16x32_bf16(af[1], bf, acc[1][nt], 0, 0, 0);
        }
    }

    if (OUT_MODE == 0) {
#pragma unroll
        for (int rt = 0; rt < 2; rt++)
#pragma unroll
            for (int i = 0; i < 4; i++) {
                int r = row0 + rt * 16 + quad * 4 + i;
                if (r < M) {
                    float ds = dscale[r];
                    u16* cp = C + (size_t)r * 128 + l15;
#pragma unroll
                    for (int nt = 0; nt < 8; nt++) cp[nt * 16] = f2bf(acc[rt][nt][i] * ds);
                }
            }
    } else if (OUT_MODE == 1) {
        float b[8], s[8], sq[8];
#pragma unroll
        for (int nt = 0; nt < 8; nt++) {
            b[nt] = bf2f(bias[nt * 16 + l15]);
            s[nt] = 0.f;
            sq[nt] = 0.f;
        }
#pragma unroll
        for (int rt = 0; rt < 2; rt++)
#pragma unroll
            for (int i = 0; i < 4; i++) {
                int r = row0 + rt * 16 + quad * 4 + i;
                if (r < M) {
                    u16* cp = C + (size_t)r * 128 + l15;
#pragma unroll
                    for (int nt = 0; nt < 8; nt++) {
                        float v = acc[rt][nt][i] + b[nt];
                        s[nt] += v;
                        sq[nt] += v * v;
                        cp[nt * 16] = f2bf(v);
                    }
                }
            }
#pragma unroll
        for (int nt = 0; nt < 8; nt++) {
            atomicAdd(&csum[nt * 16 + l15], s[nt]);
            atomicAdd(&csumsq[nt * 16 + l15], sq[nt]);
        }
        __syncthreads();
        if (tid < 128) {
            atomicAdd(&bn_sum[tid], csum[tid]);
            atomicAdd(&bn_sumsq[tid], csumsq[tid]);
        }
    } else {  // OUT_MODE 2
        float b[8];
#pragma unroll
        for (int nt = 0; nt < 8; nt++) b[nt] = bf2f(bias[nt * 16 + l15]);
        float cur[8];
#pragma unroll
        for (int nt = 0; nt < 8; nt++) cur[nt] = 0.f;
        int curg = -1;
#pragma unroll
        for (int rt = 0; rt < 2; rt++)
#pragma unroll
            for (int i = 0; i < 4; i++) {
                int r = row0 + rt * 16 + quad * 4 + i;
                if (r < M) {
                    int g = batch[r];
                    if (g != curg) {
                        if (curg >= 0) {
                            u32* bp = pooled + curg * 128 + l15;
#pragma unroll
                            for (int nt = 0; nt < 8; nt++)
                                if (cur[nt] > 0.f)
                                    atomicMax(&bp[nt * 16], __float_as_uint(cur[nt]));
                        }
                        curg = g;
#pragma unroll
                        for (int nt = 0; nt < 8; nt++) cur[nt] = 0.f;
                    }
#pragma unroll
                    for (int nt = 0; nt < 8; nt++)
                        cur[nt] = fmaxf(cur[nt], fmaxf(acc[rt][nt][i] + b[nt], 0.f));
                }
            }
        if (curg >= 0) {
            u32* bp = pooled + curg * 128 + l15;
#pragma unroll
            for (int nt = 0; nt < 8; nt++)
                if (cur[nt] > 0.f) atomicMax(&bp[nt * 16], __float_as_uint(cur[nt]));
        }
    }
}

// ---------- BN stats -> scale/shift (in place) ----------
__global__ void bnstats_kernel(float* __restrict__ bn_sum, float* __restrict__ bn_sumsq,
                               const u16* __restrict__ g1, const u16* __restrict__ be1) {
    int c = threadIdx.x;
    if (c < 128) {
        float mu = bn_sum[c] / (float)N_NODES;
        float var = bn_sumsq[c] / (float)N_NODES - mu * mu;
        float rstd = rsqrtf(var + EPS);
        float sc = rstd * bf2f(g1[c]);
        bn_sum[c] = sc;
        bn_sumsq[c] = bf2f(be1[c]) - mu * sc;
    }
}

// ---------- head part 1: zf[64,64] = pooled[64,128] @ W5 + b5 ----------
__global__ __launch_bounds__(256) void head1_kernel(const u32* __restrict__ pooled,
                                                    const u16* __restrict__ W5,
                                                    const u16* __restrict__ b5,
                                                    float* __restrict__ zf) {
    __shared__ float red[4][64];
    int g = blockIdx.x;
    int c = threadIdx.x & 63;
    int kq = threadIdx.x >> 6;
    const u32* prow = pooled + g * 128;
    float p = 0.f;
    for (int k = kq * 32; k < kq * 32 + 32; k++)
        p = fmaf(__uint_as_float(prow[k]), bf2f(W5[k * 64 + c]), p);
    red[kq][c] = p;
    __syncthreads();
    if (kq == 0) zf[g * 64 + c] = red[0][c] + red[1][c] + red[2][c] + red[3][c] + bf2f(b5[c]);
}

// ---------- head part 2 ----------
__global__ __launch_bounds__(64) void head2_kernel(const float* __restrict__ zf,
                                                   const u16* __restrict__ g2,
                                                   const u16* __restrict__ be2,
                                                   const u16* __restrict__ W6,
                                                   const u16* __restrict__ b6,
                                                   void* __restrict__ outv,
                                                   const int* __restrict__ flag) {
    __shared__ float Z[64][65];
    __shared__ float sc[64], sh[64], w6[64];
    int t = threadIdx.x;
    for (int idx = t; idx < 4096; idx += 64) Z[idx >> 6][idx & 63] = zf[idx];
    w6[t] = bf2f(W6[t]);
    __syncthreads();
    {
        float s = 0.f, sq = 0.f;
        for (int g = 0; g < 64; g++) {
            float v = Z[g][t];
            s += v;
            sq += v * v;
        }
        float mu = s * (1.f / 64.f);
        float var = sq * (1.f / 64.f) - mu * mu;
        float rstd = rsqrtf(var + EPS);
        float scale = rstd * bf2f(g2[t]);
        sc[t] = scale;
        sh[t] = bf2f(be2[t]) - mu * scale;
    }
    __syncthreads();
    float o = 0.f;
    for (int c = 0; c < 64; c++)
        o = fmaf(fmaxf(fmaf(Z[t][c], sc[c], sh[c]), 0.f), w6[c], o);
    float res = o + bf2f(b6[0]);
    if (*flag)
        ((u16*)outv)[t] = f2bf(res);
    else
        ((float*)outv)[t] = res;
}

extern "C" void kernel_launch(void* const* d_in, const int* in_sizes, int n_in, void* d_out,
                              int out_size, void* d_ws, size_t ws_size, hipStream_t stream) {
    const void* x = d_in[0];
    const int* ei = (const int*)d_in[1];
    const int* bat = (const int*)d_in[2];

    char* ws = (char*)d_ws;
    int* counts = (int*)(ws + WS_COUNTS);
    int* cursor = (int*)(ws + WS_CURSOR);
    u32* pooled = (u32*)(ws + WS_POOLED);
    float* bnsum = (float*)(ws + WS_BNSUM);
    float* bnssq = (float*)(ws + WS_BNSUMSQ);
    int* flag = (int*)(ws + WS_FLAG);
    int* offs = (int*)(ws + WS_OFFSETS);
    float* dinv = (float*)(ws + WS_DINV);
    int* partials = (int*)(ws + WS_DINV2);
    int* srcs = (int*)(ws + WS_SRCS);
    float* zf = (float*)(ws + WS_ZF);
    u16* cw = (u16*)(ws + WS_CANONW);
    u16* bufA = (u16*)(ws + WS_BUFA);
    u16* bufB = (u16*)(ws + WS_BUFB);
    u16* canonx = bufB;  // aliases bufB: dead after gemm1; bufB next written by gemm2

    const int* esrc = ei;
    const int* edst = ei + N_EDGES;

    hipMemsetAsync(ws, 0, ZERO_BYTES, stream);
    detect_kernel<<<1, 256, 0, stream>>>((const u32*)x, flag);

    convx_kernel<<<(N_NODES * 32 + 255) / 256, 256, 0, stream>>>(x, canonx, flag);
    SmallArgs sa;
    const int cw_off[16] = {CW_W1, CW_B1, CW_W2, CW_B2, CW_W3, CW_B3, CW_G1, CW_BE1,
                            CW_W4, CW_B4, CW_W5, CW_B5, CW_G2, CW_BE2, CW_W6, CW_B6};
    const int cw_n[16] = {4096, 128, 16384, 128, 16384, 128, 128, 128,
                          16384, 128, 8192, 64, 64, 64, 64, 1};
    const int cw_c[16] = {128, 0, 128, 0, 128, 0, 0, 0, 128, 0, 0, 0, 0, 0, 0, 0};
    for (int j = 0; j < 16; j++) {
        sa.src[j] = d_in[3 + j];
        sa.n[j] = cw_n[j];
        sa.off[j] = cw_off[j];
        sa.cols[j] = cw_c[j];
    }
    convs_kernel<<<64, 256, 0, stream>>>(sa, cw, flag);

    deg_kernel<<<(N_EDGES + 255) / 256, 256, 0, stream>>>(edst, counts);
    reduce_kernel<<<SCAN_BLOCKS, 256, 0, stream>>>(counts, partials);
    scanpart_kernel<<<1, 512, 0, stream>>>(partials);
    offsets_kernel<<<SCAN_BLOCKS, 256, 0, stream>>>(counts, partials, offs, dinv);
    scatter_kernel<<<(N_EDGES + 255) / 256, 256, 0, stream>>>(esrc, edst, offs, cursor, srcs);

    const int gb = (N_NODES + 127) / 128;
    // gemm1: hs1 = (x @ W1) * dinv  -> bufA
    mgemm_kernel<32, 0, 0><<<gb, 256, 0, stream>>>(canonx, cw + CW_W1, nullptr, bufA, nullptr,
                                                   nullptr, dinv, nullptr, nullptr, nullptr,
                                                   nullptr, nullptr, nullptr, nullptr, nullptr,
                                                   N_NODES);
    // gemm2 (fused conv1): x1 = relu((agg hs1 + hs1)*dinv + b1); hs2 = (x1 @ W2)*dinv -> bufB
    mgemm_kernel<128, 2, 0><<<gb, 256, 0, stream>>>(bufA, cw + CW_W2, nullptr, bufB, nullptr,
                                                    nullptr, dinv, nullptr, nullptr, nullptr,
                                                    nullptr, offs, srcs, dinv, cw + CW_B1,
                                                    N_NODES);
    // gemm3 (fused conv2): x2 = relu((agg hs2 + hs2)*dinv + b2); y3 = x2 @ W3 + b3 (+BN) -> bufA
    mgemm_kernel<128, 2, 1><<<gb, 256, 0, stream>>>(bufB, cw + CW_W3, cw + CW_B3, bufA, nullptr,
                                                    nullptr, nullptr, bnsum, bnssq, nullptr,
                                                    nullptr, offs, srcs, dinv, cw + CW_B2,
                                                    N_NODES);
    bnstats_kernel<<<1, 128, 0, stream>>>(bnsum, bnssq, cw + CW_G1, cw + CW_BE1);
    // gemm4: relu(relu(BN(y3)) @ W4 + b4) -> segment max into pooled
    mgemm_kernel<128, 1, 2><<<gb, 256, 0, stream>>>(bufA, cw + CW_W4, cw + CW_B4, nullptr, bnsum,
                                                    bnssq, nullptr, nullptr, nullptr, bat,
                                                    pooled, nullptr, nullptr, nullptr, nullptr,
                                                    N_NODES);
    // head
    head1_kernel<<<N_GRAPHS, 256, 0, stream>>>(pooled, cw + CW_W5, cw + CW_B5, zf);
    head2_kernel<<<1, 64, 0, stream>>>(zf, cw + CW_G2, cw + CW_BE2, cw + CW_W6, cw + CW_B6,
                                       d_out, flag);
}